// Round 10
// baseline (60.661 us; speedup 1.0000x reference)
//
#include <hip/hip_runtime.h>

// MetaSR scale-4, 64x64x64 feat -> 3x256x256. Exact-in-fp32: iy=y>>2,
// rel0=(y&3)*0.25, rel1=(x&3)*0.25, r_rev=0.25 -> 16 distinct MLP inputs.
// k_predw:    predw[sg][ct][12] (ct=c*9+tap, col j=(s&3)*3+rgb).
// k_conv_part: block=(chq16,sg,rowgroup4), wave=1ch, thread=4rows x 12out
//   (FMA:ds_read = 16:1), 16-wave fp32 tree reduce, bf16 partial in output
//   layout. __launch_bounds__(1024,2): R6-R8 calibration shows the 2nd arg
//   scale is {8->32, 4/default->64, 2->128} VGPRs; default's 64-cap spilled
//   ~200MB scratch (FETCH 62MB/WRITE 138MB at VGPR=64). 2 -> 128-reg cap,
//   kernel needs ~90 -> no spill, 4 waves/SIMD.
// k_combine:  4-way fixed-order sum, fully coalesced, deterministic.

#define NOUT 1728

__device__ inline unsigned bf16pack(float a, float b) {
    unsigned ua = __builtin_bit_cast(unsigned, a);
    unsigned ub = __builtin_bit_cast(unsigned, b);
    ua = (ua + 0x7FFFu + ((ua >> 16) & 1u)) >> 16;
    ub = (ub + 0x7FFFu + ((ub >> 16) & 1u)) >> 16;
    return ua | (ub << 16);
}
__device__ inline float bf16lo(unsigned v) {
    return __builtin_bit_cast(float, v << 16);
}
__device__ inline float bf16hi(unsigned v) {
    return __builtin_bit_cast(float, v & 0xFFFF0000u);
}

// ---------------- Kernel 1: predw[4][576][12] ------------------------------
// grid 432 = 16 s * 27 chunks of 64 outputs; block 256 = 64 outputs * 4 Ksplit
__global__ __launch_bounds__(256) void k_predw(
    const float* __restrict__ w1, const float* __restrict__ b1,
    const float* __restrict__ w2, const float* __restrict__ b2,
    float* __restrict__ predw)
{
    __shared__ float h[256];
    __shared__ float red[256];
    const int tid   = threadIdx.x;
    const int s     = blockIdx.x / 27;
    const int chunk = blockIdx.x - s * 27;

    const float rel0 = (float)(s >> 2) * 0.25f;
    const float rel1 = (float)(s & 3) * 0.25f;

    float pre = fmaf(w1[tid], rel0,
                fmaf(w1[256 + tid], rel1,
                fmaf(w1[512 + tid], 0.25f, b1[tid])));
    h[tid] = fmaxf(pre, 0.0f);
    __syncthreads();

    const int olocal = tid & 63;
    const int q      = tid >> 6;           // K-quarter
    const int o      = chunk * 64 + olocal;
    const float* w2c = w2 + q * 64 * NOUT + o;
    const float* hq  = h + q * 64;

    float acc = 0.0f;
    #pragma unroll 8
    for (int j = 0; j < 64; ++j)
        acc = fmaf(hq[j], w2c[j * NOUT], acc);
    red[tid] = acc;
    __syncthreads();

    if (tid < 64) {
        const int oo = chunk * 64 + tid;   // oo = ct*3 + k
        float a = red[tid] + red[tid + 64] + red[tid + 128] + red[tid + 192]
                + b2[oo];
        const int ct = oo / 3;
        const int k  = oo - ct * 3;
        predw[((s >> 2) * 576 + ct) * 12 + (s & 3) * 3 + k] = a;
    }
}

// ---------------- Kernel 2: split-K conv partials --------------------------
// grid 256: bid -> chq = bid>>6, sg = (bid>>4)&3, rg = bid&15
// block 1024 = 16 waves (1 channel each); thread = 4 rows x 12 outputs
__global__ __launch_bounds__(1024, 2) void k_conv_part(
    const float* __restrict__ feat, const float* __restrict__ predw,
    unsigned* __restrict__ part)
{
    __shared__ float  pw[1728];      // 16 ch * 108 (6.9 KB)
    __shared__ float4 red4[3072];    // 8 waves * 6 fl4 * 64 lanes (48 KB)

    const int tid  = threadIdx.x;
    const int bid  = blockIdx.x;
    const int chq  = bid >> 6;
    const int sg   = (bid >> 4) & 3;
    const int rg   = bid & 15;
    const int lane = tid & 63;             // x
    const int wq   = tid >> 6;             // 0..15 = local channel

    // stage pw slice for (sg, chq): 432 float4, coalesced
    if (tid < 432)
        ((float4*)pw)[tid] =
            ((const float4*)(predw + sg * 6912 + chq * 1728))[tid];

    // offsets + masks, rows r0-1 .. r0+4, cols x-1..x+1
    const int r0 = rg << 2;
    int xoff[3]; float xm[3];
    #pragma unroll
    for (int tc = 0; tc < 3; ++tc) {
        const int rx = lane + tc - 1;
        xm[tc] = ((unsigned)rx < 64u) ? 1.0f : 0.0f;
        xoff[tc] = rx < 0 ? 0 : (rx > 63 ? 63 : rx);
    }
    int yoff[6]; float ym[6];
    #pragma unroll
    for (int rr = 0; rr < 6; ++rr) {
        const int ry = r0 + rr - 1;
        ym[rr] = ((unsigned)ry < 64u) ? 1.0f : 0.0f;
        yoff[rr] = (ry < 0 ? 0 : (ry > 63 ? 63 : ry)) << 6;
    }
    __syncthreads();

    // feat loads: 18 per thread, coalesced per lane
    const int c = (chq << 4) | wq;
    const float* fc = feat + (c << 12);
    float f[6][3];
    #pragma unroll
    for (int rr = 0; rr < 6; ++rr)
        #pragma unroll
        for (int tc = 0; tc < 3; ++tc)
            f[rr][tc] = fc[yoff[rr] + xoff[tc]] * (ym[rr] * xm[tc]);

    // 27 wave-uniform ds_read_b128, 432 FMAs (ratio 16:1)
    float acc[4][12];
    #pragma unroll
    for (int ri = 0; ri < 4; ++ri)
        #pragma unroll
        for (int j = 0; j < 12; ++j) acc[ri][j] = 0.0f;

    const float4* pwc =
        (const float4*)pw + __builtin_amdgcn_readfirstlane(wq) * 27;
    #pragma unroll
    for (int tr = 0; tr < 3; ++tr) {
        #pragma unroll
        for (int tc = 0; tc < 3; ++tc) {
            const int tap = tr * 3 + tc;
            const float4 wA = pwc[tap * 3 + 0];
            const float4 wB = pwc[tap * 3 + 1];
            const float4 wC = pwc[tap * 3 + 2];
            #pragma unroll
            for (int ri = 0; ri < 4; ++ri) {
                const float v = f[ri + tr][tc];
                acc[ri][0]  = fmaf(v, wA.x, acc[ri][0]);
                acc[ri][1]  = fmaf(v, wA.y, acc[ri][1]);
                acc[ri][2]  = fmaf(v, wA.z, acc[ri][2]);
                acc[ri][3]  = fmaf(v, wA.w, acc[ri][3]);
                acc[ri][4]  = fmaf(v, wB.x, acc[ri][4]);
                acc[ri][5]  = fmaf(v, wB.y, acc[ri][5]);
                acc[ri][6]  = fmaf(v, wB.z, acc[ri][6]);
                acc[ri][7]  = fmaf(v, wB.w, acc[ri][7]);
                acc[ri][8]  = fmaf(v, wC.x, acc[ri][8]);
                acc[ri][9]  = fmaf(v, wC.y, acc[ri][9]);
                acc[ri][10] = fmaf(v, wC.z, acc[ri][10]);
                acc[ri][11] = fmaf(v, wC.w, acc[ri][11]);
            }
        }
    }

    // tree reduce 16 waves -> wave 0, fp32, two 24-float pieces per level
    for (int half = 8; half >= 1; half >>= 1) {
        #pragma unroll
        for (int piece = 0; piece < 2; ++piece) {
            if (wq >= half && wq < 2 * half) {
                const int base = (wq - half) * 384 + lane;
                #pragma unroll
                for (int q = 0; q < 6; ++q) {
                    const int ri = (piece << 1) + (q / 3);
                    const int m4 = (q % 3) << 2;
                    red4[base + q * 64] = make_float4(
                        acc[ri][m4], acc[ri][m4 + 1],
                        acc[ri][m4 + 2], acc[ri][m4 + 3]);
                }
            }
            __syncthreads();
            if (wq < half) {
                const int base = wq * 384 + lane;
                #pragma unroll
                for (int q = 0; q < 6; ++q) {
                    const int ri = (piece << 1) + (q / 3);
                    const int m4 = (q % 3) << 2;
                    const float4 v = red4[base + q * 64];
                    acc[ri][m4]     += v.x;
                    acc[ri][m4 + 1] += v.y;
                    acc[ri][m4 + 2] += v.z;
                    acc[ri][m4 + 3] += v.w;
                }
            }
            __syncthreads();
        }
    }

    // wave0: bf16-packed partial in OUTPUT layout
    // j = i*3+k (i = x-subpixel); pack x-pairs (i=2h, i=2h+1)
    if (wq == 0) {
        #pragma unroll
        for (int ri = 0; ri < 4; ++ri) {
            const int y = ((r0 + ri) << 2) + sg;
            #pragma unroll
            for (int k = 0; k < 3; ++k) {
                #pragma unroll
                for (int ih = 0; ih < 2; ++ih) {
                    const unsigned v = bf16pack(acc[ri][6 * ih + k],
                                                acc[ri][6 * ih + 3 + k]);
                    part[chq * 98304 + (k << 15) + (y << 7) + (lane << 1) + ih] = v;
                }
            }
        }
    }
}

// ---------------- Kernel 3: deterministic 4-way combine --------------------
// grid 96 * 1024 = 98304 threads, one x-pair each; fully coalesced
__global__ __launch_bounds__(1024) void k_combine(
    const unsigned* __restrict__ part, float* __restrict__ out)
{
    const int p = blockIdx.x * 1024 + threadIdx.x;   // 0..98303
    float s0 = 0.0f, s1 = 0.0f;
    #pragma unroll
    for (int q = 0; q < 4; ++q) {
        const unsigned v = part[q * 98304 + p];
        s0 += bf16lo(v);
        s1 += bf16hi(v);
    }
    float2 o; o.x = s0; o.y = s1;
    ((float2*)out)[p] = o;
}

extern "C" void kernel_launch(void* const* d_in, const int* in_sizes, int n_in,
                              void* d_out, int out_size, void* d_ws, size_t ws_size,
                              hipStream_t stream) {
    const float* feat = (const float*)d_in[0];
    const float* w1   = (const float*)d_in[1];
    const float* b1   = (const float*)d_in[2];
    const float* w2   = (const float*)d_in[3];
    const float* b2   = (const float*)d_in[4];
    float* out = (float*)d_out;

    float*    predw = (float*)d_ws;                       // 110592 B
    unsigned* part  = (unsigned*)((char*)d_ws + 110592);  // 1.57 MB

    hipLaunchKernelGGL(k_predw, dim3(432), dim3(256), 0, stream,
                       w1, b1, w2, b2, predw);
    hipLaunchKernelGGL(k_conv_part, dim3(256), dim3(1024), 0, stream,
                       feat, predw, part);
    hipLaunchKernelGGL(k_combine, dim3(96), dim3(1024), 0, stream,
                       part, out);
}

// Round 11
// 20.580 us; speedup vs baseline: 2.9475x; 2.9475x over previous
//
#include <hip/hip_runtime.h>

// MetaSR scale-4, 64x64x64 feat -> 3x256x256. Exact-in-fp32: iy=y>>2,
// rel0=(y&3)*0.25, rel1=(x&3)*0.25, r_rev=0.25 -> 16 distinct MLP inputs.
// k_predw:    predw[sg][ct][12] (ct=c*9+tap, col j=(s&3)*3+rgb).
// k_conv_part: 2 rows/thread so live regs (~55) FIT the 64-VGPR cap the
//   compiler imposes on 1024-thr blocks (R6-R9: cap is occupancy-derived,
//   launch_bounds cannot raise it; 4-row needed ~100 -> permanent spill).
//   grid 512 = chq4 x sg4 x rg32; 16 waves x 1ch; ratio 8 FMA : 1 ds_read;
//   16-wave fp32 tree reduce; bf16 partial in output layout.
// k_combine:  4-way fixed-order sum, fully coalesced, deterministic.

#define NOUT 1728

__device__ inline unsigned bf16pack(float a, float b) {
    unsigned ua = __builtin_bit_cast(unsigned, a);
    unsigned ub = __builtin_bit_cast(unsigned, b);
    ua = (ua + 0x7FFFu + ((ua >> 16) & 1u)) >> 16;
    ub = (ub + 0x7FFFu + ((ub >> 16) & 1u)) >> 16;
    return ua | (ub << 16);
}
__device__ inline float bf16lo(unsigned v) {
    return __builtin_bit_cast(float, v << 16);
}
__device__ inline float bf16hi(unsigned v) {
    return __builtin_bit_cast(float, v & 0xFFFF0000u);
}

// ---------------- Kernel 1: predw[4][576][12] ------------------------------
// grid 432 = 16 s * 27 chunks of 64 outputs; block 256 = 64 outputs * 4 Ksplit
__global__ __launch_bounds__(256) void k_predw(
    const float* __restrict__ w1, const float* __restrict__ b1,
    const float* __restrict__ w2, const float* __restrict__ b2,
    float* __restrict__ predw)
{
    __shared__ float h[256];
    __shared__ float red[256];
    const int tid   = threadIdx.x;
    const int s     = blockIdx.x / 27;
    const int chunk = blockIdx.x - s * 27;

    const float rel0 = (float)(s >> 2) * 0.25f;
    const float rel1 = (float)(s & 3) * 0.25f;

    float pre = fmaf(w1[tid], rel0,
                fmaf(w1[256 + tid], rel1,
                fmaf(w1[512 + tid], 0.25f, b1[tid])));
    h[tid] = fmaxf(pre, 0.0f);
    __syncthreads();

    const int olocal = tid & 63;
    const int q      = tid >> 6;           // K-quarter
    const int o      = chunk * 64 + olocal;
    const float* w2c = w2 + q * 64 * NOUT + o;
    const float* hq  = h + q * 64;

    float acc = 0.0f;
    #pragma unroll 8
    for (int j = 0; j < 64; ++j)
        acc = fmaf(hq[j], w2c[j * NOUT], acc);
    red[tid] = acc;
    __syncthreads();

    if (tid < 64) {
        const int oo = chunk * 64 + tid;   // oo = ct*3 + k
        float a = red[tid] + red[tid + 64] + red[tid + 128] + red[tid + 192]
                + b2[oo];
        const int ct = oo / 3;
        const int k  = oo - ct * 3;
        predw[((s >> 2) * 576 + ct) * 12 + (s & 3) * 3 + k] = a;
    }
}

// ---------------- Kernel 2: split-K conv partials --------------------------
// grid 512: bid -> chq = bid>>7, sg = (bid>>5)&3, rg = bid&31
// block 1024 = 16 waves (1 channel each); thread = 2 rows x 12 outputs
__global__ __launch_bounds__(1024) void k_conv_part(
    const float* __restrict__ feat, const float* __restrict__ predw,
    unsigned* __restrict__ part)
{
    __shared__ float  pw[1728];      // 16 ch * 108 (6.9 KB)
    __shared__ float4 red4[3072];    // 8 waves * 6 fl4 * 64 lanes (48 KB)

    const int tid  = threadIdx.x;
    const int bid  = blockIdx.x;
    const int chq  = bid >> 7;
    const int sg   = (bid >> 5) & 3;
    const int rg   = bid & 31;
    const int lane = tid & 63;             // x
    const int wq   = tid >> 6;             // 0..15 = local channel

    // stage pw slice for (sg, chq): 432 float4, coalesced
    if (tid < 432)
        ((float4*)pw)[tid] =
            ((const float4*)(predw + sg * 6912 + chq * 1728))[tid];

    // offsets + masks, rows r0-1 .. r0+2, cols x-1..x+1
    const int r0 = rg << 1;
    int xoff[3]; float xm[3];
    #pragma unroll
    for (int tc = 0; tc < 3; ++tc) {
        const int rx = lane + tc - 1;
        xm[tc] = ((unsigned)rx < 64u) ? 1.0f : 0.0f;
        xoff[tc] = rx < 0 ? 0 : (rx > 63 ? 63 : rx);
    }
    int yoff[4]; float ym[4];
    #pragma unroll
    for (int rr = 0; rr < 4; ++rr) {
        const int ry = r0 + rr - 1;
        ym[rr] = ((unsigned)ry < 64u) ? 1.0f : 0.0f;
        yoff[rr] = (ry < 0 ? 0 : (ry > 63 ? 63 : ry)) << 6;
    }
    __syncthreads();

    // feat loads: 12 per thread, coalesced per lane
    const int c = (chq << 4) | wq;
    const float* fc = feat + (c << 12);
    float f[4][3];
    #pragma unroll
    for (int rr = 0; rr < 4; ++rr)
        #pragma unroll
        for (int tc = 0; tc < 3; ++tc)
            f[rr][tc] = fc[yoff[rr] + xoff[tc]] * (ym[rr] * xm[tc]);

    // 27 wave-uniform ds_read_b128, 216 FMAs (ratio 8:1)
    float acc[2][12];
    #pragma unroll
    for (int ri = 0; ri < 2; ++ri)
        #pragma unroll
        for (int j = 0; j < 12; ++j) acc[ri][j] = 0.0f;

    const float4* pwc =
        (const float4*)pw + __builtin_amdgcn_readfirstlane(wq) * 27;
    #pragma unroll
    for (int tr = 0; tr < 3; ++tr) {
        #pragma unroll
        for (int tc = 0; tc < 3; ++tc) {
            const int tap = tr * 3 + tc;
            const float4 wA = pwc[tap * 3 + 0];
            const float4 wB = pwc[tap * 3 + 1];
            const float4 wC = pwc[tap * 3 + 2];
            #pragma unroll
            for (int ri = 0; ri < 2; ++ri) {
                const float v = f[ri + tr][tc];
                acc[ri][0]  = fmaf(v, wA.x, acc[ri][0]);
                acc[ri][1]  = fmaf(v, wA.y, acc[ri][1]);
                acc[ri][2]  = fmaf(v, wA.z, acc[ri][2]);
                acc[ri][3]  = fmaf(v, wA.w, acc[ri][3]);
                acc[ri][4]  = fmaf(v, wB.x, acc[ri][4]);
                acc[ri][5]  = fmaf(v, wB.y, acc[ri][5]);
                acc[ri][6]  = fmaf(v, wB.z, acc[ri][6]);
                acc[ri][7]  = fmaf(v, wB.w, acc[ri][7]);
                acc[ri][8]  = fmaf(v, wC.x, acc[ri][8]);
                acc[ri][9]  = fmaf(v, wC.y, acc[ri][9]);
                acc[ri][10] = fmaf(v, wC.z, acc[ri][10]);
                acc[ri][11] = fmaf(v, wC.w, acc[ri][11]);
            }
        }
    }

    // tree reduce 16 waves -> wave 0, fp32, 6 float4 per thread
    for (int half = 8; half >= 1; half >>= 1) {
        if (wq >= half && wq < 2 * half) {
            const int base = (wq - half) * 384 + lane;
            #pragma unroll
            for (int q = 0; q < 6; ++q) {
                const int ri = q / 3;
                const int m4 = (q % 3) << 2;
                red4[base + q * 64] = make_float4(
                    acc[ri][m4], acc[ri][m4 + 1],
                    acc[ri][m4 + 2], acc[ri][m4 + 3]);
            }
        }
        __syncthreads();
        if (wq < half) {
            const int base = wq * 384 + lane;
            #pragma unroll
            for (int q = 0; q < 6; ++q) {
                const int ri = q / 3;
                const int m4 = (q % 3) << 2;
                const float4 v = red4[base + q * 64];
                acc[ri][m4]     += v.x;
                acc[ri][m4 + 1] += v.y;
                acc[ri][m4 + 2] += v.z;
                acc[ri][m4 + 3] += v.w;
            }
        }
        __syncthreads();
    }

    // wave0: bf16-packed partial in OUTPUT layout
    // j = i*3+k (i = x-subpixel); pack x-pairs (i=2h, i=2h+1)
    if (wq == 0) {
        #pragma unroll
        for (int ri = 0; ri < 2; ++ri) {
            const int y = ((r0 + ri) << 2) + sg;
            #pragma unroll
            for (int k = 0; k < 3; ++k) {
                #pragma unroll
                for (int ih = 0; ih < 2; ++ih) {
                    const unsigned v = bf16pack(acc[ri][6 * ih + k],
                                                acc[ri][6 * ih + 3 + k]);
                    part[chq * 98304 + (k << 15) + (y << 7) + (lane << 1) + ih] = v;
                }
            }
        }
    }
}

// ---------------- Kernel 3: deterministic 4-way combine --------------------
// grid 96 * 1024 = 98304 threads, one x-pair each; fully coalesced
__global__ __launch_bounds__(1024) void k_combine(
    const unsigned* __restrict__ part, float* __restrict__ out)
{
    const int p = blockIdx.x * 1024 + threadIdx.x;   // 0..98303
    float s0 = 0.0f, s1 = 0.0f;
    #pragma unroll
    for (int q = 0; q < 4; ++q) {
        const unsigned v = part[q * 98304 + p];
        s0 += bf16lo(v);
        s1 += bf16hi(v);
    }
    float2 o; o.x = s0; o.y = s1;
    ((float2*)out)[p] = o;
}

extern "C" void kernel_launch(void* const* d_in, const int* in_sizes, int n_in,
                              void* d_out, int out_size, void* d_ws, size_t ws_size,
                              hipStream_t stream) {
    const float* feat = (const float*)d_in[0];
    const float* w1   = (const float*)d_in[1];
    const float* b1   = (const float*)d_in[2];
    const float* w2   = (const float*)d_in[3];
    const float* b2   = (const float*)d_in[4];
    float* out = (float*)d_out;

    float*    predw = (float*)d_ws;                       // 110592 B
    unsigned* part  = (unsigned*)((char*)d_ws + 110592);  // 1.57 MB

    hipLaunchKernelGGL(k_predw, dim3(432), dim3(256), 0, stream,
                       w1, b1, w2, b2, predw);
    hipLaunchKernelGGL(k_conv_part, dim3(512), dim3(1024), 0, stream,
                       feat, predw, part);
    hipLaunchKernelGGL(k_combine, dim3(96), dim3(1024), 0, stream,
                       part, out);
}

// Round 12
// 16.536 us; speedup vs baseline: 3.6685x; 1.2446x over previous
//
#include <hip/hip_runtime.h>

// MetaSR scale-4 as MFMA GEMM: out[48][4096] = W[48][576] @ U[576][4096].
// 16 distinct MLP inputs (exact in fp32) -> W rows m = s*3+k, K reordered as
// k = tap*64 + c so B-fragments (unfold U) build in registers from L2:
// per kk-step, one (tap,mask) + 8 feat loads at channel stride. No LDS,
// no barriers, no split-K, 2 launches.

#define NOUT 1728

typedef short bf16x8 __attribute__((ext_vector_type(8)));
typedef float f32x4  __attribute__((ext_vector_type(4)));

__device__ inline unsigned bf16pack(float a, float b) {
    unsigned ua = __builtin_bit_cast(unsigned, a);
    unsigned ub = __builtin_bit_cast(unsigned, b);
    ua = (ua + 0x7FFFu + ((ua >> 16) & 1u)) >> 16;
    ub = (ub + 0x7FFFu + ((ub >> 16) & 1u)) >> 16;
    return ua | (ub << 16);
}

// ---------------- Kernel 1: W as bf16, layout [m=48][k=tap*64+c] -----------
// grid 432 = 16 s * 27 chunks of 64 outputs; block 256 = 64 outputs * 4 Ksplit
__global__ __launch_bounds__(256) void k_predw(
    const float* __restrict__ w1, const float* __restrict__ b1,
    const float* __restrict__ w2, const float* __restrict__ b2,
    unsigned short* __restrict__ predw16)
{
    __shared__ float h[256];
    __shared__ float red[256];
    const int tid   = threadIdx.x;
    const int s     = blockIdx.x / 27;
    const int chunk = blockIdx.x - s * 27;

    const float rel0 = (float)(s >> 2) * 0.25f;
    const float rel1 = (float)(s & 3) * 0.25f;

    float pre = fmaf(w1[tid], rel0,
                fmaf(w1[256 + tid], rel1,
                fmaf(w1[512 + tid], 0.25f, b1[tid])));
    h[tid] = fmaxf(pre, 0.0f);
    __syncthreads();

    const int olocal = tid & 63;
    const int q      = tid >> 6;           // K-quarter
    const int o      = chunk * 64 + olocal;
    const float* w2c = w2 + q * 64 * NOUT + o;
    const float* hq  = h + q * 64;

    float acc = 0.0f;
    #pragma unroll 8
    for (int j = 0; j < 64; ++j)
        acc = fmaf(hq[j], w2c[j * NOUT], acc);
    red[tid] = acc;
    __syncthreads();

    if (tid < 64) {
        const int oo = chunk * 64 + tid;   // oo = ct*3 + k
        float a = red[tid] + red[tid + 64] + red[tid + 128] + red[tid + 192]
                + b2[oo];
        const int ct = oo / 3;
        const int k  = oo - ct * 3;
        const int c  = (ct * 7282) >> 16;  // ct/9 exact for ct<576
        const int tp = ct - c * 9;
        const int m  = s * 3 + k;
        const unsigned ub =
            (__builtin_bit_cast(unsigned, a) + 0x7FFFu +
             ((__builtin_bit_cast(unsigned, a) >> 16) & 1u)) >> 16;
        predw16[m * 576 + tp * 64 + c] = (unsigned short)ub;
    }
}

// ---------------- Kernel 2: MFMA conv ---------------------------------------
// grid 256 = n-tiles (y0 = n>>2, x0 = (n&3)*16); block 192 = 3 waves (m-tiles)
__global__ __launch_bounds__(192) void k_conv(
    const float* __restrict__ feat, const unsigned short* __restrict__ predw16,
    float* __restrict__ out)
{
    const int tid  = threadIdx.x;
    const int lane = tid & 63;
    const int mt   = tid >> 6;            // m-tile 0..2
    const int n    = blockIdx.x;          // 0..255
    const int y0   = n >> 2;
    const int x0   = (n & 3) << 4;

    const int lc = lane & 15;             // B col (cell) / A row (m)
    const int lk = lane >> 4;             // k subgroup 0..3

    // per-lane clamped addr + masks for dc,dr in {0,1,2} (offset -1)
    int xadr[3]; float xmsk[3];
    #pragma unroll
    for (int d = 0; d < 3; ++d) {
        const int rx = x0 + lc + d - 1;
        xmsk[d] = ((unsigned)rx < 64u) ? 1.0f : 0.0f;
        xadr[d] = rx < 0 ? 0 : (rx > 63 ? 63 : rx);
    }
    int yadr[3]; float ymsk[3];
    #pragma unroll
    for (int d = 0; d < 3; ++d) {
        const int ry = y0 + d - 1;
        ymsk[d] = ((unsigned)ry < 64u) ? 1.0f : 0.0f;
        yadr[d] = (ry < 0 ? 0 : (ry > 63 ? 63 : ry)) << 6;
    }

    const unsigned short* arow = predw16 + (mt * 16 + lc) * 576 + (lk << 3);

    f32x4 acc = {0.0f, 0.0f, 0.0f, 0.0f};

    #pragma unroll 2
    for (int kk = 0; kk < 18; ++kk) {
        const int tap = kk >> 1;
        const int dr  = (tap >= 6) ? 2 : (tap >= 3 ? 1 : 0);
        const int dc  = tap - dr * 3;
        const int c0  = ((kk & 1) << 5) + (lk << 3);
        const float* fb = feat + (c0 << 12) + yadr[dr] + xadr[dc];
        const float  mk = ymsk[dr] * xmsk[dc];

        float v0 = fb[0]         * mk;
        float v1 = fb[1 << 12]   * mk;
        float v2 = fb[2 << 12]   * mk;
        float v3 = fb[3 << 12]   * mk;
        float v4 = fb[4 << 12]   * mk;
        float v5 = fb[5 << 12]   * mk;
        float v6 = fb[6 << 12]   * mk;
        float v7 = fb[7 << 12]   * mk;

        uint4 bb;
        bb.x = bf16pack(v0, v1);
        bb.y = bf16pack(v2, v3);
        bb.z = bf16pack(v4, v5);
        bb.w = bf16pack(v6, v7);
        const bf16x8 bfrag = __builtin_bit_cast(bf16x8, bb);

        const bf16x8 afrag = *(const bf16x8*)(arow + 32 * kk);

        acc = __builtin_amdgcn_mfma_f32_16x16x32_bf16(afrag, bfrag, acc, 0, 0, 0);
    }

    // D: col = lane&15 (cell), row = lk*4 + r (within m-tile)
    #pragma unroll
    for (int r = 0; r < 4; ++r) {
        const int m = mt * 16 + (lk << 2) + r;
        const int s = (m * 171) >> 9;     // m/3 exact for m<48
        const int k = m - s * 3;
        const int y = (y0 << 2) + (s >> 2);
        const int x = ((x0 + lc) << 2) + (s & 3);
        out[k * 65536 + y * 256 + x] = acc[r];
    }
}

extern "C" void kernel_launch(void* const* d_in, const int* in_sizes, int n_in,
                              void* d_out, int out_size, void* d_ws, size_t ws_size,
                              hipStream_t stream) {
    const float* feat = (const float*)d_in[0];
    const float* w1   = (const float*)d_in[1];
    const float* b1   = (const float*)d_in[2];
    const float* w2   = (const float*)d_in[3];
    const float* b2   = (const float*)d_in[4];
    float* out = (float*)d_out;
    unsigned short* predw16 = (unsigned short*)d_ws;  // 48*576*2 = 55296 B

    hipLaunchKernelGGL(k_predw, dim3(432), dim3(256), 0, stream,
                       w1, b1, w2, b2, predw16);
    hipLaunchKernelGGL(k_conv, dim3(256), dim3(192), 0, stream,
                       feat, predw16, out);
}